// Round 1
// baseline (147.330 us; speedup 1.0000x reference)
//
#include <hip/hip_runtime.h>
#include <hip/hip_bf16.h>
#include <cstddef>

#define T_TOK 1024
#define D_DIM 1024
#define H_DIM 512
#define E_EXP 8
#define P_CAP 2560          // max padded pairs: 2048 + 8*31 = 2296 -> 2560
#define MAX_MT 72           // 32-row m-tiles: <= 2296/32 = 71.75 -> 72 slots
#define LDA 72              // shorts per LDS row: 64 data + 8 pad (144B, 16B-aligned)
#define NK1 16              // gemm1 K-steps: 1024/64
#define NK2 8               // gemm2 K-steps: 512/64

typedef __attribute__((ext_vector_type(4))) float    float4_t;
typedef __attribute__((ext_vector_type(8))) short    short8_t;
typedef __attribute__((ext_vector_type(4))) unsigned uint4_t;
typedef __attribute__((ext_vector_type(2))) unsigned uint2_t;

__device__ __forceinline__ short f2bf(float f) {
  union { float f; unsigned u; } v; v.f = f;
  unsigned u = v.u;
  u += 0x7FFFu + ((u >> 16) & 1u);
  return (short)(u >> 16);
}

// packed fp32x2 -> bf16x2; low short = a, high = b
__device__ __forceinline__ unsigned pkbf(float a, float b) {
  union { __hip_bfloat162 h; unsigned u; } v;
  v.h = __float22bfloat162_rn(make_float2(a, b));
  return v.u;
}

// ---- prep: weight transpose+convert (z<24) + router (z==24) + out=0 (z==25)
// tile stride 69 floats (odd) keeps transpose reads <=2-way.
__global__ __launch_bounds__(256) void prep_kernel(
    const float* __restrict__ w1, const float* __restrict__ w3,
    const float* __restrict__ w2, const float* __restrict__ x,
    const float* __restrict__ gw, short* __restrict__ w13t,
    short* __restrict__ w2t, int* __restrict__ idx2,
    float* __restrict__ scale2, float* __restrict__ out) {
  __shared__ float tile[64][69];
  const int z = blockIdx.z;
  const int tid = threadIdx.x;

  if (z < 24) {
    const float* src; short* dst; int N, ldd, row_off;
    if (z < 16) {
      if (blockIdx.y >= 8) return;          // N=512 -> 8 n-tiles
      int which = z >> 3, e = z & 7;
      src = (which ? w3 : w1) + (size_t)e * D_DIM * H_DIM;
      dst = w13t + (size_t)e * D_DIM * (2 * H_DIM);
      N = H_DIM; ldd = D_DIM; row_off = which ? H_DIM : 0;
    } else {
      if (blockIdx.x >= 8) return;          // K=512 -> 8 k-tiles
      int e = z - 16;
      src = w2 + (size_t)e * H_DIM * D_DIM;
      dst = w2t + (size_t)e * D_DIM * H_DIM;
      N = D_DIM; ldd = H_DIM; row_off = 0;
    }
    const int k0 = blockIdx.x * 64, n0 = blockIdx.y * 64;
    const int kr = tid >> 4, nc = (tid & 15) * 4;
    #pragma unroll
    for (int p = 0; p < 4; ++p) {
      int k = p * 16 + kr;
      float4_t v = *(const float4_t*)(src + (size_t)(k0 + k) * N + n0 + nc);
      tile[k][nc]     = v[0];
      tile[k][nc + 1] = v[1];
      tile[k][nc + 2] = v[2];
      tile[k][nc + 3] = v[3];
    }
    __syncthreads();
    const int r8 = tid >> 3, c8 = tid & 7;
    #pragma unroll
    for (int p = 0; p < 2; ++p) {
      int row = p * 32 + r8;
      uint4_t u;
      #pragma unroll
      for (int jj = 0; jj < 4; ++jj)
        u[jj] = pkbf(tile[c8 * 8 + 2 * jj][row], tile[c8 * 8 + 2 * jj + 1][row]);
      *(uint4_t*)(dst + (size_t)(row_off + n0 + row) * ldd + k0 + c8 * 8) = u;
    }
    return;
  }

  if (z == 25) {                            // zero out[] : 256 blocks x 16KB
    float4_t z4 = {0.f, 0.f, 0.f, 0.f};
    float4_t* o = (float4_t*)(out + ((size_t)(blockIdx.y * 16 + blockIdx.x)) * 4096);
    #pragma unroll
    for (int i = 0; i < 4; ++i) o[i * 256 + tid] = z4;
    return;
  }

  // z == 24: router, 4 tokens per block (one wave each)
  const int wid  = tid >> 6;
  const int lane = tid & 63;
  const int t = (blockIdx.y * 16 + blockIdx.x) * 4 + wid;
  const float* xr = x + (size_t)t * D_DIM;
  float acc[E_EXP];
  #pragma unroll
  for (int e = 0; e < E_EXP; ++e) acc[e] = 0.f;
  for (int d = lane; d < D_DIM; d += 64) {
    float xv = xr[d];
    float4_t g0 = *(const float4_t*)(gw + d * E_EXP);
    float4_t g1 = *(const float4_t*)(gw + d * E_EXP + 4);
    acc[0] += xv * g0[0]; acc[1] += xv * g0[1];
    acc[2] += xv * g0[2]; acc[3] += xv * g0[3];
    acc[4] += xv * g1[0]; acc[5] += xv * g1[1];
    acc[6] += xv * g1[2]; acc[7] += xv * g1[3];
  }
  #pragma unroll
  for (int off = 32; off >= 1; off >>= 1) {
    #pragma unroll
    for (int e = 0; e < E_EXP; ++e) acc[e] += __shfl_down(acc[e], off, 64);
  }
  if (lane == 0) {
    float m = acc[0];
    #pragma unroll
    for (int e = 1; e < E_EXP; ++e) m = fmaxf(m, acc[e]);
    float p[E_EXP]; float s = 0.f;
    #pragma unroll
    for (int e = 0; e < E_EXP; ++e) { p[e] = __expf(acc[e] - m); s += p[e]; }
    float inv = 1.f / s;
    #pragma unroll
    for (int e = 0; e < E_EXP; ++e) p[e] *= inv;
    int i1 = 0;
    #pragma unroll
    for (int e = 1; e < E_EXP; ++e) if (p[e] > p[i1]) i1 = e;  // jax low-index tiebreak
    int i2 = (i1 == 0) ? 1 : 0;
    #pragma unroll
    for (int e = 0; e < E_EXP; ++e) {
      if (e == i1 || e == i2) continue;
      if (p[e] > p[i2]) i2 = e;
    }
    idx2[2 * t]     = i1;  scale2[2 * t]     = p[i1];
    idx2[2 * t + 1] = i2;  scale2[2 * t + 1] = p[i2];
  }
}

// ---- scan/assign: histogram -> 32-aligned bases -> tile table -> pair lists
__global__ __launch_bounds__(256) void scan_kernel(
    const int* __restrict__ idx2, const float* __restrict__ scale2,
    int* __restrict__ pair_tok, float* __restrict__ pair_scale,
    int* __restrict__ meta) {
  __shared__ int cnt[E_EXP], base[E_EXP], cur[E_EXP];
  const int tid = threadIdx.x;
  if (tid < E_EXP) { cnt[tid] = 0; cur[tid] = 0; }
  for (int p = tid; p < P_CAP; p += 256) { pair_tok[p] = -1; pair_scale[p] = 0.f; }
  __syncthreads();
  for (int t = tid; t < T_TOK; t += 256) {
    atomicAdd(&cnt[idx2[2 * t]], 1);
    atomicAdd(&cnt[idx2[2 * t + 1]], 1);
  }
  __syncthreads();
  if (tid == 0) {
    int b = 0, g = 0;
    for (int e = 0; e < E_EXP; ++e) {
      base[e] = b;
      int al = (cnt[e] + 31) & ~31;       // 32-row tiles
      for (int j = 0; j < al; j += 32) { meta[1 + g] = e; meta[81 + g] = b + j; ++g; }
      b += al;
    }
    meta[0] = g;  // n_mtiles (<= 72)
  }
  __syncthreads();
  for (int t = tid; t < T_TOK; t += 256) {
    #pragma unroll
    for (int s = 0; s < 2; ++s) {
      int e = idx2[2 * t + s];
      int p = base[e] + atomicAdd(&cur[e], 1);
      pair_tok[p] = t;
      pair_scale[p] = scale2[2 * t + s];
    }
  }
}

// ---- astage: Ag[p][D] = bf16(scale[p] * x[tok[p]]), once, instead of
// re-gathering + re-converting in all 16 gemm1 n-tile blocks.
// 8 rows/block, 320 blocks; per-thread 8 independent float4 loads (ILP).
__global__ __launch_bounds__(256) void astage_kernel(
    const float* __restrict__ x, const int* __restrict__ pair_tok,
    const float* __restrict__ pair_scale, short* __restrict__ Ag) {
  const int tid = threadIdx.x;
  const int row = blockIdx.x * 8 + (tid >> 5);
  const int c0  = (tid & 31) * 4;
  const int   tok = pair_tok[row];
  const float sc  = pair_scale[row];            // 0 for pad rows -> zeros
  const float* xr = x + (size_t)(tok < 0 ? 0 : tok) * D_DIM;
  short* orow = Ag + (size_t)row * D_DIM;
  #pragma unroll
  for (int j = 0; j < 8; ++j) {
    int c = c0 + j * 128;
    float4_t v = *(const float4_t*)(xr + c);
    uint2_t u = { pkbf(v[0] * sc, v[1] * sc), pkbf(v[2] * sc, v[3] * sc) };
    *(uint2_t*)(orow + c) = u;
  }
}

// ------- gemm1: h[p][H] = silu(A@w1e) * (A@w3e); 32m x 32n ----------------
// 2-phase: double-buffered LDS, ONE barrier per K-step; next-tile global
// loads issued between barrier and MFMA so their latency hides under compute.
__global__ __launch_bounds__(256, 5) void gemm1_kernel(
    const short* __restrict__ Ag, const short* __restrict__ w13t,
    const int* __restrict__ meta, short* __restrict__ h) {
  __shared__ short As[2][32 * LDA];    // 2 x 4.6 KB
  __shared__ short B1s[2][32 * LDA];   // 2 x 4.6 KB
  __shared__ short B3s[2][32 * LDA];   // 2 x 4.6 KB  -> 27.6 KB total
  const int mt = blockIdx.y;
  if (mt >= meta[0]) return;
  const int e    = meta[1 + mt];
  const int row0 = meta[81 + mt];
  const int n0   = blockIdx.x * 32;
  const int tid = threadIdx.x, lane = tid & 63, wid = tid >> 6;
  const int wr = wid >> 1, wc = wid & 1;        // 2x2 waves, each 16m x 16n
  const int q = lane >> 4, ln = lane & 15;
  const short* bsrc = w13t + (size_t)e * D_DIM * (2 * H_DIM);

  // staging: thread owns one 8-short k-unit of one row (plain bf16 copy now)
  const int sr = tid >> 3, sk = (tid & 7) * 8;
  const short* ap  = Ag   + (size_t)(row0 + sr) * D_DIM + sk;
  const short* b1p = bsrc + (size_t)(n0 + sr) * D_DIM + sk;
  const short* b3p = bsrc + (size_t)(H_DIM + n0 + sr) * D_DIM + sk;

  float4_t acc1 = {0.f, 0.f, 0.f, 0.f}, acc3 = {0.f, 0.f, 0.f, 0.f};

  {                                            // prologue: stage tile 0
    uint4_t va = *(const uint4_t*)ap;
    uint4_t v1 = *(const uint4_t*)b1p;
    uint4_t v3 = *(const uint4_t*)b3p;
    *(uint4_t*)&As[0][sr * LDA + sk]  = va;
    *(uint4_t*)&B1s[0][sr * LDA + sk] = v1;
    *(uint4_t*)&B3s[0][sr * LDA + sk] = v3;
  }

  for (int t = 0; t < NK1 - 1; ++t) {
    __syncthreads();                           // buf[t&1] ready for all waves
    const int cur = t & 1, nxt = cur ^ 1;
    const int ko = (t + 1) * 64;
    uint4_t wa  = *(const uint4_t*)(ap + ko);  // issue early: hides under MFMA
    uint4_t w1v = *(const uint4_t*)(b1p + ko);
    uint4_t w3v = *(const uint4_t*)(b3p + ko);

    short8_t af[2], b1f[2], b3f[2];
    #pragma unroll
    for (int kk = 0; kk < 2; ++kk) {
      af[kk]  = *(const short8_t*)&As[cur][(wr * 16 + ln) * LDA + kk * 32 + q * 8];
      b1f[kk] = *(const short8_t*)&B1s[cur][(wc * 16 + ln) * LDA + kk * 32 + q * 8];
      b3f[kk] = *(const short8_t*)&B3s[cur][(wc * 16 + ln) * LDA + kk * 32 + q * 8];
    }
    #pragma unroll
    for (int kk = 0; kk < 2; ++kk) {
      acc1 = __builtin_amdgcn_mfma_f32_16x16x32_bf16(af[kk], b1f[kk], acc1, 0, 0, 0);
      acc3 = __builtin_amdgcn_mfma_f32_16x16x32_bf16(af[kk], b3f[kk], acc3, 0, 0, 0);
    }
    *(uint4_t*)&As[nxt][sr * LDA + sk]  = wa;  // vmcnt wait covered by MFMAs
    *(uint4_t*)&B1s[nxt][sr * LDA + sk] = w1v;
    *(uint4_t*)&B3s[nxt][sr * LDA + sk] = w3v;
  }
  __syncthreads();                             // last tile in buf 1 (15&1)
  {
    short8_t af[2], b1f[2], b3f[2];
    #pragma unroll
    for (int kk = 0; kk < 2; ++kk) {
      af[kk]  = *(const short8_t*)&As[1][(wr * 16 + ln) * LDA + kk * 32 + q * 8];
      b1f[kk] = *(const short8_t*)&B1s[1][(wc * 16 + ln) * LDA + kk * 32 + q * 8];
      b3f[kk] = *(const short8_t*)&B3s[1][(wc * 16 + ln) * LDA + kk * 32 + q * 8];
    }
    #pragma unroll
    for (int kk = 0; kk < 2; ++kk) {
      acc1 = __builtin_amdgcn_mfma_f32_16x16x32_bf16(af[kk], b1f[kk], acc1, 0, 0, 0);
      acc3 = __builtin_amdgcn_mfma_f32_16x16x32_bf16(af[kk], b3f[kk], acc3, 0, 0, 0);
    }
  }

  {
    int r_base = row0 + wr * 16 + q * 4;
    int col = n0 + wc * 16 + ln;
    #pragma unroll
    for (int rr = 0; rr < 4; ++rr) {
      float c1 = acc1[rr];
      float c3 = acc3[rr];
      float sig = 1.f / (1.f + __expf(-c1));
      h[(size_t)(r_base + rr) * H_DIM + col] = f2bf(c1 * sig * c3);
    }
  }
}

// -- gemm2 (fused combine): out[tok] += h[p][H] @ w2t[e]; 32m x 64n ----------
// Same 2-phase single-barrier double-buffer structure.
__global__ __launch_bounds__(256, 5) void gemm2_kernel(
    const short* __restrict__ h, const short* __restrict__ w2t,
    const int* __restrict__ pair_tok, const int* __restrict__ meta,
    float* __restrict__ out) {
  __shared__ short As[2][32 * LDA];   // 2 x 4.6 KB
  __shared__ short Bs[2][64 * LDA];   // 2 x 9.2 KB -> 27.6 KB total
  const int mt = blockIdx.y;
  if (mt >= meta[0]) return;
  const int e    = meta[1 + mt];
  const int row0 = meta[81 + mt];
  const int n0   = blockIdx.x * 64;
  const int tid = threadIdx.x, lane = tid & 63, wid = tid >> 6;
  const int wr = wid >> 1, wc = wid & 1;        // 2x2 waves, each 16m x 32n
  const int q = lane >> 4, ln = lane & 15;
  const short* bsrc = w2t + (size_t)e * D_DIM * H_DIM;  // [1024 n][512 k]

  const int ar = tid >> 3, ak = (tid & 7) * 8;
  const short* arow = h + (size_t)(row0 + ar) * H_DIM + ak;
  const int br = tid >> 2, bk = (tid & 3) * 16;
  const short* brow = bsrc + (size_t)(n0 + br) * H_DIM + bk;

  float4_t acc[2];
  acc[0] = acc[1] = (float4_t){0.f, 0.f, 0.f, 0.f};

  {                                            // prologue: stage tile 0
    uint4_t va  = *(const uint4_t*)arow;
    uint4_t vb0 = *(const uint4_t*)brow;
    uint4_t vb1 = *(const uint4_t*)(brow + 8);
    *(uint4_t*)&As[0][ar * LDA + ak]     = va;
    *(uint4_t*)&Bs[0][br * LDA + bk]     = vb0;
    *(uint4_t*)&Bs[0][br * LDA + bk + 8] = vb1;
  }

  for (int t = 0; t < NK2 - 1; ++t) {
    __syncthreads();
    const int cur = t & 1, nxt = cur ^ 1;
    const int ko = (t + 1) * 64;
    uint4_t wa  = *(const uint4_t*)(arow + ko);
    uint4_t wb0 = *(const uint4_t*)(brow + ko);
    uint4_t wb1 = *(const uint4_t*)(brow + ko + 8);

    short8_t af[2], bf[2][2];
    #pragma unroll
    for (int kk = 0; kk < 2; ++kk) {
      af[kk] = *(const short8_t*)&As[cur][(wr * 16 + ln) * LDA + kk * 32 + q * 8];
      #pragma unroll
      for (int j = 0; j < 2; ++j)
        bf[j][kk] = *(const short8_t*)&Bs[cur][(wc * 32 + j * 16 + ln) * LDA + kk * 32 + q * 8];
    }
    #pragma unroll
    for (int j = 0; j < 2; ++j)
      #pragma unroll
      for (int kk = 0; kk < 2; ++kk)
        acc[j] = __builtin_amdgcn_mfma_f32_16x16x32_bf16(af[kk], bf[j][kk], acc[j], 0, 0, 0);

    *(uint4_t*)&As[nxt][ar * LDA + ak]     = wa;
    *(uint4_t*)&Bs[nxt][br * LDA + bk]     = wb0;
    *(uint4_t*)&Bs[nxt][br * LDA + bk + 8] = wb1;
  }
  __syncthreads();                             // last tile in buf 1 (7&1)
  {
    short8_t af[2], bf[2][2];
    #pragma unroll
    for (int kk = 0; kk < 2; ++kk) {
      af[kk] = *(const short8_t*)&As[1][(wr * 16 + ln) * LDA + kk * 32 + q * 8];
      #pragma unroll
      for (int j = 0; j < 2; ++j)
        bf[j][kk] = *(const short8_t*)&Bs[1][(wc * 32 + j * 16 + ln) * LDA + kk * 32 + q * 8];
    }
    #pragma unroll
    for (int j = 0; j < 2; ++j)
      #pragma unroll
      for (int kk = 0; kk < 2; ++kk)
        acc[j] = __builtin_amdgcn_mfma_f32_16x16x32_bf16(af[kk], bf[j][kk], acc[j], 0, 0, 0);
  }

  // ---- epilogue: scatter-add into out[tok]; skip pad rows (tok < 0)
  {
    int r_base = row0 + wr * 16 + q * 4;
    #pragma unroll
    for (int rr = 0; rr < 4; ++rr) {
      int tok = pair_tok[r_base + rr];
      if (tok < 0) continue;
      float* orow = out + (size_t)tok * D_DIM;
      #pragma unroll
      for (int j = 0; j < 2; ++j) {
        int col = n0 + wc * 32 + j * 16 + ln;
        atomicAdd(orow + col, acc[j][rr]);
      }
    }
  }
}

extern "C" void kernel_launch(void* const* d_in, const int* in_sizes, int n_in,
                              void* d_out, int out_size, void* d_ws, size_t ws_size,
                              hipStream_t stream) {
  const float* x  = (const float*)d_in[0];   // [2,512,1024]
  const float* gw = (const float*)d_in[1];   // [1024,8]
  const float* w1 = (const float*)d_in[2];   // [8,1024,512] gate
  const float* w2 = (const float*)d_in[3];   // [8,512,1024] down
  const float* w3 = (const float*)d_in[4];   // [8,1024,512] up
  float* out = (float*)d_out;

  char* ws = (char*)d_ws;
  int*   idx2    = (int*)  (ws);                       // 8KB
  float* scale2  = (float*)(ws + 8192);                // 8KB
  int*   ptok    = (int*)  (ws + 16384);               // 10KB (16KB slot)
  float* pscale  = (float*)(ws + 32768);               // 10KB (16KB slot)
  int*   meta    = (int*)  (ws + 49152);               // 640B (16KB slot)
  short* h       = (short*)(ws + (1u << 20));          // 2.62 MB
  short* w13t    = (short*)(ws + (4u << 20));          // 16.8 MB
  short* w2t     = (short*)(ws + (21u << 20));         // 8.4 MB
  short* Ag      = (short*)(ws + (30u << 20));         // 5.24 MB scaled-bf16 A

  prep_kernel<<<dim3(16, 16, 26), dim3(256), 0, stream>>>(
      w1, w3, w2, x, gw, w13t, w2t, idx2, scale2, out);
  scan_kernel<<<dim3(1), dim3(256), 0, stream>>>(idx2, scale2, ptok, pscale, meta);
  astage_kernel<<<dim3(P_CAP / 8), dim3(256), 0, stream>>>(x, ptok, pscale, Ag);
  gemm1_kernel<<<dim3(H_DIM / 32, MAX_MT), dim3(256), 0, stream>>>(
      Ag, w13t, meta, h);
  gemm2_kernel<<<dim3(D_DIM / 64, MAX_MT), dim3(256), 0, stream>>>(
      h, w2t, ptok, meta, out);
}